// Round 1
// 1023.815 us; speedup vs baseline: 1.4988x; 1.4988x over previous
//
#include <hip/hip_runtime.h>
#include <hip/hip_bf16.h>

#define NN 20000
#define NE 320000
#define NT 2048            // filter LUT entries over len in [0, 1.7321]

typedef _Float16 h2f __attribute__((ext_vector_type(2)));

__device__ __forceinline__ h2f u2h(unsigned int u){
  union { unsigned int u; h2f h; } v; v.u = u; return v.h;
}
__device__ __forceinline__ unsigned int h2u(h2f h){
  union { h2f h; unsigned int u; } v; v.h = h; return v.u;
}
__device__ __forceinline__ unsigned int pack2(float a, float b){
  h2f h; h.x = (_Float16)a; h.y = (_Float16)b;
  union { h2f h; unsigned int u; } v; v.h = h; return v.u;
}
__device__ __forceinline__ unsigned short f16b(float a){
  union { _Float16 h; unsigned short u; } v; v.h = (_Float16)a; return v.u;
}
__device__ __forceinline__ float dot2(unsigned int w, h2f x, float acc){
#if __has_builtin(__builtin_amdgcn_fdot2)
  return __builtin_amdgcn_fdot2(u2h(w), x, acc, false);
#else
  h2f c = u2h(w);
  return acc + (float)(c.x) * (float)(x.x) + (float)(c.y) * (float)(x.y);
#endif
}
// packed f16 lerp: a + t*(b-a)
__device__ __forceinline__ unsigned int lerp2(unsigned int a, unsigned int b, h2f t){
  h2f ha = u2h(a), hb = u2h(b);
  return h2u(ha + t * (hb - ha));
}

// jax.nn.gelu default (approximate=True): 0.5x(1+tanh(t)) == x*sigmoid(2t)
__device__ __forceinline__ float geluf(float x){
  float t = 0.7978845608028654f * x * (1.0f + 0.044715f * x * x);
  return x / (1.0f + __expf(-2.0f * t));
}

// ---------------- weight transpose/copy (fp32 -> fp32 in ws) ----------------
struct TEnt { const float* src; float* dst; int R; int C; int trans; };
struct TTab { TEnt e[16]; };

__global__ void convw(TTab t){
  TEnt en = t.e[blockIdx.x];
  int n = en.R * en.C;
  for (int i = threadIdx.x; i < n; i += blockDim.x){
    float v = en.src[i];
    if (en.trans){
      int r = i / en.C, c = i - r * en.C;
      en.dst[c * en.R + r] = v;          // dst[C][R]
    } else {
      en.dst[i] = v;
    }
  }
}

// ---------------- pack fp32 [R][C] -> f16-pair uints [C][R/2] ---------------
struct PEnt { const float* src; unsigned int* dst; int R; int C; };
struct PTab { PEnt e[10]; };

__global__ void packw(PTab t){
  PEnt en = t.e[blockIdx.x];
  int half = en.R >> 1;
  int n = en.C * half;
  for (int i = threadIdx.x; i < n; i += blockDim.x){
    int c = i / half, rp = i - c * half;
    float a = en.src[(2*rp)     * en.C + c];
    float b = en.src[(2*rp + 1) * en.C + c];
    en.dst[i] = pack2(a, b);
  }
}

// ---------------- filter LUT build ------------------------------------------
// layer LUT row (per entry): f16 halves [Wa 96 | Wb 96 | Wc 192] = 384 h = 768B
// entry i built at len = max(i*TMAX/(NT-1), 1e-6)  (matches ref r_safe path)
__device__ __forceinline__ void lut_basis(int ent, float* b){
  float len = fmaxf((float)ent * (1.7321f / (float)(NT - 1)), 1e-6f);
  float sc = 3.1622776601683795f / fmaxf(len, 1e-6f);  // sqrt(2/MAXR)*sqrt(B)/r
#pragma unroll
  for (int k = 0; k < 10; k++)
    b[k] = sinf((float)(k + 1) * 1.5707963267948966f * len) * sc;
}

__global__ __launch_bounds__(384) void build_lut(
    const float* __restrict__ fABw1 /*[L][2][10][64]*/,
    const float* __restrict__ fABw2 /*[L][2][64][96]*/,
    const float* __restrict__ fCw1  /*[L][10][64]*/,
    const float* __restrict__ fCw2  /*[L][64][192]*/,
    unsigned short* __restrict__ lutH)
{
  int ent = blockIdx.x & (NT - 1);
  int layer = blockIdx.x >> 11;       // NT = 2048
  float b[10];
  lut_basis(ent, b);
  __shared__ float h[192];
  int t = threadIdx.x;
  if (t < 192){
    int f = t >> 6, l = t & 63;       // f: 0=A, 1=B, 2=C
    const float* w1 = (f < 2) ? (fABw1 + (layer*2 + f) * 640)
                              : (fCw1 + layer * 640);
    float a = 0.f;
#pragma unroll
    for (int k = 0; k < 10; k++) a += b[k] * w1[k*64 + l];
    h[t] = geluf(a);
  }
  __syncthreads();
  float a = 0.f;
  if (t < 192){
    int f = t / 96, j = t - 96 * f;
    const float* w2 = fABw2 + (layer*2 + f) * 6144;
    for (int l = 0; l < 64; l++) a += h[f*64 + l] * w2[l*96 + j];
  } else {
    int j = t - 192;
    const float* w2 = fCw2 + layer * 12288;
    for (int l = 0; l < 64; l++) a += h[128 + l] * w2[l*192 + j];
  }
  lutH[((long)(layer * NT + ent)) * 384 + t] = f16b(a);
}

// init LUT row: f16 halves [W0 32 | W1 32] = 64 h = 128B
__global__ __launch_bounds__(64) void build_lut01(
    const float* __restrict__ f01w1 /*[2][10][64]*/,
    const float* __restrict__ f01w2 /*[2][64][32]*/,
    unsigned short* __restrict__ lutH)
{
  int ent = blockIdx.x, t = threadIdx.x;
  int p = t >> 5, jj = t & 31;
  float b[10];
  lut_basis(ent, b);
  const float* w1 = f01w1 + p * 640;
  const float* w2 = f01w2 + p * 2048;
  float W = 0.f;
  for (int l = 0; l < 64; l++){
    float a = 0.f;
#pragma unroll
    for (int k = 0; k < 10; k++) a += b[k] * w1[k*64 + l];
    W += geluf(a) * w2[l*32 + jj];
  }
  lutH[(long)ent * 64 + t] = f16b(W);
}

// ---------------- CSR build --------------------------------------------------
__global__ void count_k(const int* __restrict__ esrc, const int* __restrict__ edst,
                        int* __restrict__ cnt){
  int e = blockIdx.x * 256 + threadIdx.x;
  if (e >= NE) return;
  atomicAdd(cnt + edst[e], 1);
  atomicAdd(cnt + esrc[e], 1);
}

__global__ __launch_bounds__(1024) void prefix_k(const int* __restrict__ cnt,
                                                 int* __restrict__ off, int* __restrict__ cur){
  __shared__ int part[1024];
  int t = threadIdx.x;
  int base = t * 20;
  int s = 0;
  for (int i = 0; i < 20; i++){ int idx = base + i; if (idx < NN) s += cnt[idx]; }
  part[t] = s; __syncthreads();
  for (int d = 1; d < 1024; d <<= 1){
    int v = (t >= d) ? part[t - d] : 0;
    __syncthreads();
    part[t] += v;
    __syncthreads();
  }
  int run = (t == 0) ? 0 : part[t - 1];
  for (int i = 0; i < 20; i++){
    int idx = base + i;
    if (idx < NN){ off[idx] = run; cur[idx] = run; run += cnt[idx]; }
  }
  if (t == 0) off[NN] = 2 * NE;
}

__global__ void fill_k(const int* __restrict__ esrc, const int* __restrict__ edst,
                       int* __restrict__ cur, int* __restrict__ inc){
  int e = blockIdx.x * 256 + threadIdx.x;
  if (e >= NE) return;
  int pd = atomicAdd(cur + edst[e], 1);
  inc[pd] = (e << 1);          // role 0: this node is dst
  int ps = atomicAdd(cur + esrc[e], 1);
  inc[ps] = (e << 1) | 1;      // role 1: this node is src
}

// ---------------- node init: xn[:,0:32] = mlp2(embed[z]), zero rest ---------
__global__ __launch_bounds__(256) void node_init(
    const int* __restrict__ az, const float* __restrict__ embedF,
    const float* __restrict__ w1T /*[32][8]*/, const float* __restrict__ w2T /*[32][32]*/,
    float* __restrict__ xn)
{
  int n = blockIdx.x * 256 + threadIdx.x;
  if (n >= NN) return;
  int z = az[n];
  float ee[8];
#pragma unroll
  for (int k = 0; k < 8; k++) ee[k] = embedF[z * 8 + k];
  float hid[32];
#pragma unroll
  for (int l = 0; l < 32; l++){
    float a = 0.f;
#pragma unroll
    for (int k = 0; k < 8; k++) a += ee[k] * w1T[l * 8 + k];
    hid[l] = geluf(a);
  }
  float* row = xn + (long)n * 96;
#pragma unroll
  for (int j = 0; j < 32; j++){
    float a = 0.f;
#pragma unroll
    for (int l = 0; l < 32; l++) a += hid[l] * w2T[j * 32 + l];
    row[j] = a;
  }
#pragma unroll
  for (int j = 32; j < 96; j++) row[j] = 0.f;
}

// ---------------- edge init: per-edge f16 messages (64 halves = 128B) -------
// msg[e-e0][0:32]  = W0 * xeh / 16     (div payload, sign applied gather-side)
// msg[e-e0][32:64] = 0.5 * W1 * xeh/16 (ave payload)
__global__ __launch_bounds__(256) void edge_init(
    const float* __restrict__ pos, const int* __restrict__ esrc, const int* __restrict__ edst,
    unsigned short* __restrict__ msgh, int e0, int e1,
    const float* __restrict__ w1T /*dl1w1T [32][4]*/, const float* __restrict__ w2T /*[32][32]*/,
    const unsigned int* __restrict__ lut01)
{
  int e = e0 + blockIdx.x * 256 + threadIdx.x;
  if (e >= e1) return;
  int s = esrc[e], d = edst[e];
  float x = pos[s*3+0] - pos[d*3+0];
  float y = pos[s*3+1] - pos[d*3+1];
  float z = pos[s*3+2] - pos[d*3+2];
  float L = sqrtf(x*x + y*y + z*z + 1e-12f);
  float iv = 1.0f / fmaxf(L, 1e-6f);

  float u = L - 2.0f;   // 2*(len/MAXR - 1), MAXR=2
  float cut = 0.5f * (1.0f - cosf(3.14159265358979323f * u));
  cut = (u > 0.0f) ? 0.0f : cut;
  cut = (u < -1.0f) ? 1.0f : cut;
  float xe0 = cut, cc = cut * 1.7320508075688772f * iv;
  float xe1 = cc*x, xe2 = cc*y, xe3 = cc*z;
  float hid[32];
#pragma unroll
  for (int l = 0; l < 32; l++){
    float a = xe0*w1T[l*4+0] + xe1*w1T[l*4+1] + xe2*w1T[l*4+2] + xe3*w1T[l*4+3];
    hid[l] = geluf(a);
  }
  float xeh[32];
#pragma unroll
  for (int j = 0; j < 32; j++){
    float a = 0.f;
#pragma unroll
    for (int l = 0; l < 32; l++) a += hid[l] * w2T[j*32 + l];
    xeh[j] = a;
  }
  // LUT lerp setup
  float tt = fminf(L * ((float)(NT-1) / 1.7321f), (float)(NT-1) - 0.001f);
  int i0 = (int)tt; float tfv = tt - (float)i0;
  h2f tf2; tf2.x = (_Float16)tfv; tf2.y = tf2.x;
  h2f h05; h05.x = (_Float16)0.5f; h05.y = h05.x;
  const unsigned int* rA = lut01 + i0 * 32;
  const unsigned int* rB = rA + 32;

  unsigned int xp[16];
#pragma unroll
  for (int jp = 0; jp < 16; jp++)
    xp[jp] = pack2(xeh[2*jp] * 0.0625f, xeh[2*jp+1] * 0.0625f);

  unsigned short* mrow = msgh + (long)(e - e0) * 64;
  {
    unsigned int du[16];
#pragma unroll
    for (int q = 0; q < 4; q++){
      uint4 a = ((const uint4*)rA)[q];
      uint4 b = ((const uint4*)rB)[q];
      du[4*q+0] = h2u(u2h(lerp2(a.x, b.x, tf2)) * u2h(xp[4*q+0]));
      du[4*q+1] = h2u(u2h(lerp2(a.y, b.y, tf2)) * u2h(xp[4*q+1]));
      du[4*q+2] = h2u(u2h(lerp2(a.z, b.z, tf2)) * u2h(xp[4*q+2]));
      du[4*q+3] = h2u(u2h(lerp2(a.w, b.w, tf2)) * u2h(xp[4*q+3]));
    }
    uint4* dd = (uint4*)mrow;
#pragma unroll
    for (int q = 0; q < 4; q++) dd[q] = ((uint4*)du)[q];
  }
  {
    unsigned int au[16];
#pragma unroll
    for (int q = 0; q < 4; q++){
      uint4 a = ((const uint4*)(rA + 16))[q];
      uint4 b = ((const uint4*)(rB + 16))[q];
      au[4*q+0] = h2u(u2h(lerp2(a.x, b.x, tf2)) * u2h(xp[4*q+0]) * h05);
      au[4*q+1] = h2u(u2h(lerp2(a.y, b.y, tf2)) * u2h(xp[4*q+1]) * h05);
      au[4*q+2] = h2u(u2h(lerp2(a.z, b.z, tf2)) * u2h(xp[4*q+2]) * h05);
      au[4*q+3] = h2u(u2h(lerp2(a.w, b.w, tf2)) * u2h(xp[4*q+3]) * h05);
    }
    uint4* dd = (uint4*)(mrow + 32);
#pragma unroll
    for (int q = 0; q < 4; q++) dd[q] = ((uint4*)au)[q];
  }
}

// one block (64 threads) per node; cols 32..95 of xn accumulate
__global__ __launch_bounds__(64) void gather_init(
    const int* __restrict__ inc, const int* __restrict__ off,
    const unsigned short* __restrict__ msgh, float* __restrict__ xn, int e0, int e1)
{
  int n = blockIdx.x;
  int c = threadIdx.x;          // 0..63
  int i0 = off[n], i1 = off[n+1];
  const _Float16* mh = (const _Float16*)msgh;
  float acc = 0.f;
  for (int ii = i0; ii < i1; ii++){
    int v = inc[ii];
    int e = v >> 1;
    if (e < e0 || e >= e1) continue;
    float m = (float)mh[(long)(e - e0) * 64 + c];
    float sgn = (c < 32 && (v & 1)) ? -1.0f : 1.0f;
    acc += sgn * m;
  }
  xn[(long)n * 96 + 32 + c] += 16.f * acc;   // undo 1/16 msg scale
}

// ---------------- conv layer with filter-LUT --------------------------------
// msg row = 192 f16 halves (384B): p=[0,96) by dst, q=[96,192) by src
// stored value = true/64 (undone in gather_layer)
// pk layout per layer (uints): dw1T[32][96] @0, dw2[192][16] @3072 (6144 total)
// lut row per entry (uints):   WaPairs[48] | WbPairs[48] | WcPairs[96] (192)
__global__ __launch_bounds__(512, 4) void layer_k(
    const float* __restrict__ pos, const int* __restrict__ esrc,
    const int* __restrict__ edst, const float* __restrict__ xn,
    unsigned short* __restrict__ msgh, int e0, int e1,
    const unsigned int* __restrict__ lut, const unsigned int* __restrict__ pk)
{
  __shared__ uint4 lw4[1536];          // 24 KB: dw1T + dw2
  unsigned int* lw = (unsigned int*)lw4;
  int t = threadIdx.x;
  {
    const uint4* s4 = (const uint4*)pk;
    for (int i = t; i < 1536; i += 512) lw4[i] = s4[i];
  }
  __syncthreads();
  int e = e0 + blockIdx.x * 512 + t;
  if (e >= e1) return;

  const unsigned int* dw1T = lw;          // [32][96]
  const unsigned int* dw2  = lw + 3072;   // [192][16]

  int s = esrc[e], d = edst[e];
  float px = pos[s*3+0] - pos[d*3+0];
  float py = pos[s*3+1] - pos[d*3+1];
  float pz = pos[s*3+2] - pos[d*3+2];
  float L = sqrtf(px*px + py*py + pz*pz + 1e-12f);
  float tt = fminf(L * ((float)(NT-1) / 1.7321f), (float)(NT-1) - 0.001f);
  int i0 = (int)tt; float tfv = tt - (float)i0;
  h2f tf2; tf2.x = (_Float16)tfv; tf2.y = tf2.x;
  const unsigned int* rA = lut + (long)i0 * 192;
  const unsigned int* rB = rA + 192;

  const float* xsr = xn + (long)s * 96;
  const float* xdr = xn + (long)d * 96;

  float hd[32];
#pragma unroll
  for (int l = 0; l < 32; l++) hd[l] = 0.f;

  // ---- merged A(grad)/B(ave) pass: hd += dw1T^T @ [Wa*(xd-xs); Wb*(xd+xs)/2]
  // g packed at 1/32 scale -> hd holds true/32
  for (int jc = 0; jc < 96; jc += 8){
    float4 t0 = *(const float4*)(xsr + jc);
    float4 t1 = *(const float4*)(xsr + jc + 4);
    float4 u0 = *(const float4*)(xdr + jc);
    float4 u1 = *(const float4*)(xdr + jc + 4);
    float xs[8] = {t0.x,t0.y,t0.z,t0.w,t1.x,t1.y,t1.z,t1.w};
    float xd[8] = {u0.x,u0.y,u0.z,u0.w,u1.x,u1.y,u1.z,u1.w};
    int jh = jc >> 1;
    uint4 aA = *(const uint4*)(rA + jh);
    uint4 bA = *(const uint4*)(rB + jh);
    uint4 aB = *(const uint4*)(rA + 48 + jh);
    uint4 bB = *(const uint4*)(rB + 48 + jh);
    unsigned int wA[4] = {lerp2(aA.x,bA.x,tf2), lerp2(aA.y,bA.y,tf2),
                          lerp2(aA.z,bA.z,tf2), lerp2(aA.w,bA.w,tf2)};
    unsigned int wB[4] = {lerp2(aB.x,bB.x,tf2), lerp2(aB.y,bB.y,tf2),
                          lerp2(aB.z,bB.z,tf2), lerp2(aB.w,bB.w,tf2)};
    h2f gpA[4], gpB[4];
#pragma unroll
    for (int p = 0; p < 4; p++){
      h2f dv2, av2;
      dv2.x = (_Float16)((xd[2*p]   - xs[2*p]  ) * 0.03125f);
      dv2.y = (_Float16)((xd[2*p+1] - xs[2*p+1]) * 0.03125f);
      av2.x = (_Float16)((xd[2*p]   + xs[2*p]  ) * 0.015625f);
      av2.y = (_Float16)((xd[2*p+1] + xs[2*p+1]) * 0.015625f);
      gpA[p] = u2h(wA[p]) * dv2;
      gpB[p] = u2h(wB[p]) * av2;
    }
#pragma unroll
    for (int l = 0; l < 32; l++){
      uint4 w1 = *(const uint4*)(dw1T + l*96 + jh);
      uint4 w2 = *(const uint4*)(dw1T + l*96 + 48 + jh);
      float acc = hd[l];
      acc = dot2(w1.x, gpA[0], acc); acc = dot2(w1.y, gpA[1], acc);
      acc = dot2(w1.z, gpA[2], acc); acc = dot2(w1.w, gpA[3], acc);
      acc = dot2(w2.x, gpB[0], acc); acc = dot2(w2.y, gpB[1], acc);
      acc = dot2(w2.z, gpB[2], acc); acc = dot2(w2.w, gpB[3], acc);
      hd[l] = acc;
    }
  }

  // ---- hd gelu (undo 1/32), pack at 1/64 for output dots ----
  h2f hdp[16];
#pragma unroll
  for (int lp = 0; lp < 16; lp++){
    h2f r;
    r.x = (_Float16)(geluf(32.f*hd[2*lp])   * 0.015625f);
    r.y = (_Float16)(geluf(32.f*hd[2*lp+1]) * 0.015625f);
    hdp[lp] = r;
  }

  // ---- output: dv = Wc[j]*d1, av = 0.5*Wc[96+j]*d2; store p/q at true/64 ---
  unsigned short* mrow = msgh + (long)(e - e0) * 192;
  for (int c0 = 0; c0 < 96; c0 += 32){
    unsigned int pu[16], qu[16];
#pragma unroll
    for (int q4 = 0; q4 < 4; q4++){
      int cb = 96 + (c0 >> 1) + 4*q4;
      uint4 a1 = *(const uint4*)(rA + cb);
      uint4 b1 = *(const uint4*)(rB + cb);
      uint4 a2 = *(const uint4*)(rA + cb + 48);
      uint4 b2 = *(const uint4*)(rB + cb + 48);
      unsigned int c1l[4] = {lerp2(a1.x,b1.x,tf2), lerp2(a1.y,b1.y,tf2),
                             lerp2(a1.z,b1.z,tf2), lerp2(a1.w,b1.w,tf2)};
      unsigned int c2l[4] = {lerp2(a2.x,b2.x,tf2), lerp2(a2.y,b2.y,tf2),
                             lerp2(a2.z,b2.z,tf2), lerp2(a2.w,b2.w,tf2)};
#pragma unroll
      for (int r4 = 0; r4 < 4; r4++){
        int jp = 4*q4 + r4;
        h2f c1h = u2h(c1l[r4]);
        h2f c2h = u2h(c2l[r4]);
        float pv2[2], qv2[2];
#pragma unroll
        for (int w = 0; w < 2; w++){
          int j = c0 + 2*jp + w;
          float d1 = 0.f, d2 = 0.f;
          const uint4* r1 = (const uint4*)(dw2 + j*16);
          const uint4* r2 = (const uint4*)(dw2 + (96+j)*16);
#pragma unroll
          for (int q = 0; q < 4; q++){
            uint4 wa = r1[q], wb = r2[q];
            d1 = dot2(wa.x, hdp[4*q+0], d1); d1 = dot2(wa.y, hdp[4*q+1], d1);
            d1 = dot2(wa.z, hdp[4*q+2], d1); d1 = dot2(wa.w, hdp[4*q+3], d1);
            d2 = dot2(wb.x, hdp[4*q+0], d2); d2 = dot2(wb.y, hdp[4*q+1], d2);
            d2 = dot2(wb.z, hdp[4*q+2], d2); d2 = dot2(wb.w, hdp[4*q+3], d2);
          }
          float c1 = w ? (float)c1h.y : (float)c1h.x;
          float c2 = w ? (float)c2h.y : (float)c2h.x;
          float dv = c1 * d1;           // true/64
          float av = 0.5f * c2 * d2;    // true/64
          pv2[w] = dv + av;
          qv2[w] = av - dv;
        }
        pu[jp] = pack2(pv2[0], pv2[1]);
        qu[jp] = pack2(qv2[0], qv2[1]);
      }
    }
    uint4* pd = (uint4*)(mrow + c0);        // line-aligned full 64B
    uint4* qd = (uint4*)(mrow + 96 + c0);   // line-aligned full 64B
#pragma unroll
    for (int q = 0; q < 4; q++){
      pd[q] = ((uint4*)pu)[q];
      qd[q] = ((uint4*)qu)[q];
    }
  }
}

// one block (128 threads, 96 active) per node; accumulate into delta
__global__ __launch_bounds__(128) void gather_layer(
    const int* __restrict__ inc, const int* __restrict__ off,
    const unsigned short* __restrict__ msgh, float* __restrict__ delta, int e0, int e1)
{
  int n = blockIdx.x;
  int c = threadIdx.x;
  if (c >= 96) return;
  int i0 = off[n], i1 = off[n+1];
  const _Float16* mh = (const _Float16*)msgh;
  float acc = 0.f;
  for (int ii = i0; ii < i1; ii++){
    int v = inc[ii];
    int e = v >> 1;
    if (e < e0 || e >= e1) continue;
    acc += (float)mh[(long)(e - e0) * 192 + (v & 1) * 96 + c];
  }
  delta[(long)n * 96 + c] += 64.f * acc;   // undo 1/64 msg scale
}

// ---------------- xn -= h*delta; re-zero delta ------------------------------
__global__ void node_upd(float* __restrict__ xn, float* __restrict__ delta){
  int i = blockIdx.x * 256 + threadIdx.x;
  if (i < NN * 96){
    xn[i] -= 0.1f * delta[i];
    delta[i] = 0.f;
  }
}

// ---------------- column sum over nodes -------------------------------------
__global__ void colsum(const float* __restrict__ xn, float* __restrict__ nodesum){
  int col = threadIdx.x % 96;
  int seg = threadIdx.x / 96;
  int stripe = blockIdx.x * 2 + seg;   // 0..399
  float acc = 0.f;
  for (int n = stripe; n < NN; n += 400) acc += xn[(long)n * 96 + col];
  unsafeAtomicAdd(nodesum + col, acc);
}

// ---------------- project to 16 outputs, scale, fp32 store ------------------
__global__ void project(const float* __restrict__ nodesum, const float* __restrict__ siT,
                        float* __restrict__ out){
  int j = threadIdx.x;
  if (j < 16){
    float a = 0.f;
#pragma unroll
    for (int c = 0; c < 96; c++) a += nodesum[c] * siT[j*96 + c];
    out[j] = a * 0.007071067811865475f;   // 1/sqrt(20000)
  }
}

// ---------------- host side -------------------------------------------------
extern "C" void kernel_launch(void* const* d_in, const int* in_sizes, int n_in,
                              void* d_out, int out_size, void* d_ws, size_t ws_size,
                              hipStream_t stream){
  const float* pos  = (const float*)d_in[0];
  const int* atom_z = (const int*)d_in[1];
  const int* esrc   = (const int*)d_in[2];
  const int* edst   = (const int*)d_in[3];

  float* ws      = (float*)d_ws;
  float* xn      = ws;                  // NN*96 = 1,920,000
  float* delta   = ws + 1920000;        // NN*96
  float* nodesum = ws + 3840000;        // 96
  float* WB      = ws + 3840096;        // 4,128 fp32 weights
  unsigned int* pk    = (unsigned int*)(ws + 3844224);  // 2*6144 packed uints
  unsigned int* lutL  = (unsigned int*)(ws + 3856512);  // 2*2048*192 uints (3 MB)
  unsigned int* lut01 = (unsigned int*)(ws + 4642944);  // 2048*32 uints
  int*   cnt     = (int*)(ws + 4708480);        // 20,000
  int*   cur     = cnt + 20000;                 // 20,000
  int*   off     = cur + 20000;                 // 20,004 (pad)
  int*   inc     = off + 20004;                 // 640,000
  unsigned short* msgh = (unsigned short*)(ws + 5408496);  // 64B-aligned f16 msgs

  long wsFloats  = (long)(ws_size / 4);
  long msgHalves = (wsFloats - 5408496L) * 2;
  if (msgHalves < 192 * 1024) msgHalves = 192 * 1024;  // last-resort floor
  long CE  = msgHalves / 192; if (CE > NE) CE = NE;    // layer chunk (192 h/edge)
  long CEi = msgHalves / 64;  if (CEi > NE) CEi = NE;  // init chunk  (64 h/edge)

  float* embedF = WB + 0;        // 160
  float* dl0w1T = WB + 160;      // 256   [32][8]
  float* dl0w2T = WB + 416;      // 1024  [32][32]
  float* dl1w1T = WB + 1440;     // 128   [32][4]
  float* dl1w2T = WB + 1568;     // 1024  [32][32]
  float* siT    = WB + 2592;     // 1536  [16][96]

  hipMemsetAsync(cnt, 0, 20000 * 4, stream);
  hipMemsetAsync(delta, 0, (size_t)NN * 96 * 4, stream);
  hipMemsetAsync(nodesum, 0, 96 * 4, stream);

  TTab tb;
  int ti = 0;
  auto add = [&](const void* s, float* dst, int R, int C, int tr){
    tb.e[ti].src = (const float*)s; tb.e[ti].dst = dst;
    tb.e[ti].R = R; tb.e[ti].C = C; tb.e[ti].trans = tr; ti++;
  };
  add(d_in[4],  embedF, 20, 8, 0);
  add(d_in[5],  dl0w1T, 8, 32, 1);
  add(d_in[6],  dl0w2T, 32, 32, 1);
  add(d_in[7],  dl1w1T, 4, 32, 1);
  add(d_in[8],  dl1w2T, 32, 32, 1);
  add(d_in[17], siT, 96, 16, 1);

  PTab pt;
  int pi = 0;
  auto padd = [&](const void* s, unsigned int* dst, int R, int C){
    pt.e[pi].src = (const float*)s; pt.e[pi].dst = dst;
    pt.e[pi].R = R; pt.e[pi].C = C; pi++;
  };
  for (int i = 0; i < 2; i++){
    padd((const float*)d_in[15] + i*6144, pk + i*6144 + 0,    192, 32);  // dw1T [32][96]
    padd((const float*)d_in[16] + i*6144, pk + i*6144 + 3072, 32, 192);  // dw2  [192][16]
  }

  convw<<<6, 256, 0, stream>>>(tb);
  packw<<<4, 256, 0, stream>>>(pt);
  build_lut<<<2*NT, 384, 0, stream>>>((const float*)d_in[11], (const float*)d_in[12],
                                      (const float*)d_in[13], (const float*)d_in[14],
                                      (unsigned short*)lutL);
  build_lut01<<<NT, 64, 0, stream>>>((const float*)d_in[9], (const float*)d_in[10],
                                     (unsigned short*)lut01);
  count_k<<<(NE + 255)/256, 256, 0, stream>>>(esrc, edst, cnt);
  prefix_k<<<1, 1024, 0, stream>>>(cnt, off, cur);
  fill_k<<<(NE + 255)/256, 256, 0, stream>>>(esrc, edst, cur, inc);
  node_init<<<(NN + 255)/256, 256, 0, stream>>>(atom_z, embedF, dl0w1T, dl0w2T, xn);

  for (long e0 = 0; e0 < NE; e0 += CEi){
    long e1 = e0 + CEi; if (e1 > NE) e1 = NE;
    edge_init<<<(int)((e1 - e0 + 255)/256), 256, 0, stream>>>(
        pos, esrc, edst, msgh, (int)e0, (int)e1, dl1w1T, dl1w2T, lut01);
    gather_init<<<NN, 64, 0, stream>>>(inc, off, msgh, xn, (int)e0, (int)e1);
  }

  for (int i = 0; i < 2; i++){
    for (long e0 = 0; e0 < NE; e0 += CE){
      long e1 = e0 + CE; if (e1 > NE) e1 = NE;
      layer_k<<<(int)((e1 - e0 + 511)/512), 512, 0, stream>>>(
          pos, esrc, edst, xn, msgh, (int)e0, (int)e1,
          lutL + (long)i * NT * 192, pk + i*6144);
      gather_layer<<<NN, 128, 0, stream>>>(inc, off, msgh, delta, (int)e0, (int)e1);
    }
    node_upd<<<(NN*96 + 255)/256, 256, 0, stream>>>(xn, delta);
  }
  colsum<<<200, 192, 0, stream>>>(xn, nodesum);
  project<<<1, 64, 0, stream>>>(nodesum, siT, (float*)d_out);
}

// Round 3
// 960.617 us; speedup vs baseline: 1.5974x; 1.0658x over previous
//
#include <hip/hip_runtime.h>
#include <hip/hip_bf16.h>

#define NN 20000
#define NE 320000
#define NT 2048            // filter LUT entries over len in [0, 1.7321]

typedef _Float16 h2f __attribute__((ext_vector_type(2)));

__device__ __forceinline__ h2f u2h(unsigned int u){
  union { unsigned int u; h2f h; } v; v.u = u; return v.h;
}
__device__ __forceinline__ unsigned int h2u(h2f h){
  union { h2f h; unsigned int u; } v; v.h = h; return v.u;
}
__device__ __forceinline__ unsigned int pack2(float a, float b){
  h2f h; h.x = (_Float16)a; h.y = (_Float16)b;
  union { h2f h; unsigned int u; } v; v.h = h; return v.u;
}
__device__ __forceinline__ unsigned short f16b(float a){
  union { _Float16 h; unsigned short u; } v; v.h = (_Float16)a; return v.u;
}
__device__ __forceinline__ float dot2(unsigned int w, h2f x, float acc){
#if __has_builtin(__builtin_amdgcn_fdot2)
  return __builtin_amdgcn_fdot2(u2h(w), x, acc, false);
#else
  h2f c = u2h(w);
  return acc + (float)(c.x) * (float)(x.x) + (float)(c.y) * (float)(x.y);
#endif
}
// packed f16 lerp: a + t*(b-a)
__device__ __forceinline__ unsigned int lerp2(unsigned int a, unsigned int b, h2f t){
  h2f ha = u2h(a), hb = u2h(b);
  return h2u(ha + t * (hb - ha));
}

// jax.nn.gelu default (approximate=True): 0.5x(1+tanh(t)) == x*sigmoid(2t)
__device__ __forceinline__ float geluf(float x){
  float t = 0.7978845608028654f * x * (1.0f + 0.044715f * x * x);
  return x / (1.0f + __expf(-2.0f * t));
}

// ---------------- weight transpose/copy (fp32 -> fp32 in ws) ----------------
struct TEnt { const float* src; float* dst; int R; int C; int trans; };
struct TTab { TEnt e[16]; };

__global__ void convw(TTab t){
  TEnt en = t.e[blockIdx.x];
  int n = en.R * en.C;
  for (int i = threadIdx.x; i < n; i += blockDim.x){
    float v = en.src[i];
    if (en.trans){
      int r = i / en.C, c = i - r * en.C;
      en.dst[c * en.R + r] = v;          // dst[C][R]
    } else {
      en.dst[i] = v;
    }
  }
}

// ---------------- pack fp32 [R][C] -> f16-pair uints [C][R/2] ---------------
struct PEnt { const float* src; unsigned int* dst; int R; int C; };
struct PTab { PEnt e[10]; };

__global__ void packw(PTab t){
  PEnt en = t.e[blockIdx.x];
  int half = en.R >> 1;
  int n = en.C * half;
  for (int i = threadIdx.x; i < n; i += blockDim.x){
    int c = i / half, rp = i - c * half;
    float a = en.src[(2*rp)     * en.C + c];
    float b = en.src[(2*rp + 1) * en.C + c];
    en.dst[i] = pack2(a, b);
  }
}

// ---------------- filter LUT build ------------------------------------------
__device__ __forceinline__ void lut_basis(int ent, float* b){
  float len = fmaxf((float)ent * (1.7321f / (float)(NT - 1)), 1e-6f);
  float sc = 3.1622776601683795f / fmaxf(len, 1e-6f);  // sqrt(2/MAXR)*sqrt(B)/r
#pragma unroll
  for (int k = 0; k < 10; k++)
    b[k] = sinf((float)(k + 1) * 1.5707963267948966f * len) * sc;
}

__global__ __launch_bounds__(384) void build_lut(
    const float* __restrict__ fABw1 /*[L][2][10][64]*/,
    const float* __restrict__ fABw2 /*[L][2][64][96]*/,
    const float* __restrict__ fCw1  /*[L][10][64]*/,
    const float* __restrict__ fCw2  /*[L][64][192]*/,
    unsigned short* __restrict__ lutH)
{
  int ent = blockIdx.x & (NT - 1);
  int layer = blockIdx.x >> 11;       // NT = 2048
  float b[10];
  lut_basis(ent, b);
  __shared__ float h[192];
  int t = threadIdx.x;
  if (t < 192){
    int f = t >> 6, l = t & 63;       // f: 0=A, 1=B, 2=C
    const float* w1 = (f < 2) ? (fABw1 + (layer*2 + f) * 640)
                              : (fCw1 + layer * 640);
    float a = 0.f;
#pragma unroll
    for (int k = 0; k < 10; k++) a += b[k] * w1[k*64 + l];
    h[t] = geluf(a);
  }
  __syncthreads();
  float a = 0.f;
  if (t < 192){
    int f = t / 96, j = t - 96 * f;
    const float* w2 = fABw2 + (layer*2 + f) * 6144;
    for (int l = 0; l < 64; l++) a += h[f*64 + l] * w2[l*96 + j];
  } else {
    int j = t - 192;
    const float* w2 = fCw2 + layer * 12288;
    for (int l = 0; l < 64; l++) a += h[128 + l] * w2[l*192 + j];
  }
  lutH[((long)(layer * NT + ent)) * 384 + t] = f16b(a);
}

// init LUT row: f16 halves [W0 32 | W1 32] = 64 h = 128B
__global__ __launch_bounds__(64) void build_lut01(
    const float* __restrict__ f01w1 /*[2][10][64]*/,
    const float* __restrict__ f01w2 /*[2][64][32]*/,
    unsigned short* __restrict__ lutH)
{
  int ent = blockIdx.x, t = threadIdx.x;
  int p = t >> 5, jj = t & 31;
  float b[10];
  lut_basis(ent, b);
  const float* w1 = f01w1 + p * 640;
  const float* w2 = f01w2 + p * 2048;
  float W = 0.f;
  for (int l = 0; l < 64; l++){
    float a = 0.f;
#pragma unroll
    for (int k = 0; k < 10; k++) a += b[k] * w1[k*64 + l];
    W += geluf(a) * w2[l*32 + jj];
  }
  lutH[(long)ent * 64 + t] = f16b(W);
}

// ---------------- CSR build (dst-sorted edge order) -------------------------
__global__ void count_k(const int* __restrict__ esrc, const int* __restrict__ edst,
                        int* __restrict__ cntd, int* __restrict__ cnts){
  int e = blockIdx.x * 256 + threadIdx.x;
  if (e >= NE) return;
  atomicAdd(cntd + edst[e], 1);
  atomicAdd(cnts + esrc[e], 1);
}

__global__ __launch_bounds__(1024) void prefix_k(const int* __restrict__ cnt,
                                                 int* __restrict__ off, int* __restrict__ cur,
                                                 int total){
  __shared__ int part[1024];
  int t = threadIdx.x;
  int base = t * 20;
  int s = 0;
  for (int i = 0; i < 20; i++){ int idx = base + i; if (idx < NN) s += cnt[idx]; }
  part[t] = s; __syncthreads();
  for (int d = 1; d < 1024; d <<= 1){
    int v = (t >= d) ? part[t - d] : 0;
    __syncthreads();
    part[t] += v;
    __syncthreads();
  }
  int run = (t == 0) ? 0 : part[t - 1];
  for (int i = 0; i < 20; i++){
    int idx = base + i;
    if (idx < NN){ off[idx] = run; cur[idx] = run; run += cnt[idx]; }
  }
  if (t == 0) off[NN] = total;
}

// p = dst-sorted position of edge e; srcS/dstS in sorted order; sinc: for each
// node (as src), list of sorted positions of its outgoing edges
__global__ void fill_comb(const int* __restrict__ esrc, const int* __restrict__ edst,
                          int* __restrict__ curd, int* __restrict__ curs,
                          int* __restrict__ srcS, int* __restrict__ dstS,
                          int* __restrict__ sinc){
  int e = blockIdx.x * 256 + threadIdx.x;
  if (e >= NE) return;
  int s = esrc[e], d = edst[e];
  int p = atomicAdd(curd + d, 1);
  srcS[p] = s; dstS[p] = d;
  int q = atomicAdd(curs + s, 1);
  sinc[q] = p;
}

// ---------------- node init: xn[:,0:32] = mlp2(embed[z]), zero rest ---------
__global__ __launch_bounds__(256) void node_init(
    const int* __restrict__ az, const float* __restrict__ embedF,
    const float* __restrict__ w1T /*[32][8]*/, const float* __restrict__ w2T /*[32][32]*/,
    float* __restrict__ xn)
{
  int n = blockIdx.x * 256 + threadIdx.x;
  if (n >= NN) return;
  int z = az[n];
  float ee[8];
#pragma unroll
  for (int k = 0; k < 8; k++) ee[k] = embedF[z * 8 + k];
  float hid[32];
#pragma unroll
  for (int l = 0; l < 32; l++){
    float a = 0.f;
#pragma unroll
    for (int k = 0; k < 8; k++) a += ee[k] * w1T[l * 8 + k];
    hid[l] = geluf(a);
  }
  float* row = xn + (long)n * 96;
#pragma unroll
  for (int j = 0; j < 32; j++){
    float a = 0.f;
#pragma unroll
    for (int l = 0; l < 32; l++) a += hid[l] * w2T[j * 32 + l];
    row[j] = a;
  }
#pragma unroll
  for (int j = 32; j < 96; j++) row[j] = 0.f;
}

// ---------------- edge init (sorted order): 64-half msgs + edge length ------
// msg[p-e0][0:32]  = W0 * xeh / 16     (div: dst +, src -)
// msg[p-e0][32:64] = 0.5 * W1 * xeh/16 (ave: both +)
__global__ __launch_bounds__(256) void edge_init(
    const float* __restrict__ pos, const int* __restrict__ srcS,
    const int* __restrict__ dstS, float* __restrict__ els,
    unsigned short* __restrict__ msgh, int e0, int e1,
    const float* __restrict__ w1T /*dl1w1T [32][4]*/, const float* __restrict__ w2T /*[32][32]*/,
    const unsigned int* __restrict__ lut01)
{
  int p = e0 + blockIdx.x * 256 + threadIdx.x;
  if (p >= e1) return;
  int s = srcS[p], d = dstS[p];
  float x = pos[s*3+0] - pos[d*3+0];
  float y = pos[s*3+1] - pos[d*3+1];
  float z = pos[s*3+2] - pos[d*3+2];
  float L = sqrtf(x*x + y*y + z*z + 1e-12f);
  float iv = 1.0f / fmaxf(L, 1e-6f);
  els[p] = L;

  float u = L - 2.0f;   // 2*(len/MAXR - 1), MAXR=2
  float cut = 0.5f * (1.0f - cosf(3.14159265358979323f * u));
  cut = (u > 0.0f) ? 0.0f : cut;
  cut = (u < -1.0f) ? 1.0f : cut;
  float xe0 = cut, cc = cut * 1.7320508075688772f * iv;
  float xe1 = cc*x, xe2 = cc*y, xe3 = cc*z;
  float hid[32];
#pragma unroll
  for (int l = 0; l < 32; l++){
    float a = xe0*w1T[l*4+0] + xe1*w1T[l*4+1] + xe2*w1T[l*4+2] + xe3*w1T[l*4+3];
    hid[l] = geluf(a);
  }
  float xeh[32];
#pragma unroll
  for (int j = 0; j < 32; j++){
    float a = 0.f;
#pragma unroll
    for (int l = 0; l < 32; l++) a += hid[l] * w2T[j*32 + l];
    xeh[j] = a;
  }
  float tt = fminf(L * ((float)(NT-1) / 1.7321f), (float)(NT-1) - 0.001f);
  int i0 = (int)tt; float tfv = tt - (float)i0;
  h2f tf2; tf2.x = (_Float16)tfv; tf2.y = tf2.x;
  h2f h05; h05.x = (_Float16)0.5f; h05.y = h05.x;
  const unsigned int* rA = lut01 + i0 * 32;
  const unsigned int* rB = rA + 32;

  unsigned int xp[16];
#pragma unroll
  for (int jp = 0; jp < 16; jp++)
    xp[jp] = pack2(xeh[2*jp] * 0.0625f, xeh[2*jp+1] * 0.0625f);

  unsigned short* mrow = msgh + (long)(p - e0) * 64;
  {
    unsigned int du[16];
#pragma unroll
    for (int q = 0; q < 4; q++){
      uint4 a = ((const uint4*)rA)[q];
      uint4 b = ((const uint4*)rB)[q];
      du[4*q+0] = h2u(u2h(lerp2(a.x, b.x, tf2)) * u2h(xp[4*q+0]));
      du[4*q+1] = h2u(u2h(lerp2(a.y, b.y, tf2)) * u2h(xp[4*q+1]));
      du[4*q+2] = h2u(u2h(lerp2(a.z, b.z, tf2)) * u2h(xp[4*q+2]));
      du[4*q+3] = h2u(u2h(lerp2(a.w, b.w, tf2)) * u2h(xp[4*q+3]));
    }
    uint4* dd = (uint4*)mrow;
#pragma unroll
    for (int q = 0; q < 4; q++) dd[q] = ((uint4*)du)[q];
  }
  {
    unsigned int au[16];
#pragma unroll
    for (int q = 0; q < 4; q++){
      uint4 a = ((const uint4*)(rA + 16))[q];
      uint4 b = ((const uint4*)(rB + 16))[q];
      au[4*q+0] = h2u(u2h(lerp2(a.x, b.x, tf2)) * u2h(xp[4*q+0]) * h05);
      au[4*q+1] = h2u(u2h(lerp2(a.y, b.y, tf2)) * u2h(xp[4*q+1]) * h05);
      au[4*q+2] = h2u(u2h(lerp2(a.z, b.z, tf2)) * u2h(xp[4*q+2]) * h05);
      au[4*q+3] = h2u(u2h(lerp2(a.w, b.w, tf2)) * u2h(xp[4*q+3]) * h05);
    }
    uint4* dd = (uint4*)(mrow + 32);
#pragma unroll
    for (int q = 0; q < 4; q++) dd[q] = ((uint4*)au)[q];
  }
}

// 4 nodes per 256-thread block; dst role streams contiguous sorted rows
__global__ __launch_bounds__(256) void gather_init(
    const int* __restrict__ doff, const int* __restrict__ soff,
    const int* __restrict__ sinc, const unsigned short* __restrict__ msgh,
    float* __restrict__ xn, int e0, int e1)
{
  int n = blockIdx.x * 4 + (threadIdx.x >> 6);
  int c = threadIdx.x & 63;
  if (n >= NN) return;
  const _Float16* mh = (const _Float16*)msgh;
  float acc = 0.f;
  int lo = doff[n], hi = doff[n+1];
  if (lo < e0) lo = e0;
  if (hi > e1) hi = e1;
  for (int p = lo; p < hi; p++) acc += (float)mh[(long)(p - e0) * 64 + c];
  int s1 = soff[n+1];
  for (int ii = soff[n]; ii < s1; ii++){
    int p = sinc[ii];
    if (p < e0 || p >= e1) continue;
    float m = (float)mh[(long)(p - e0) * 64 + c];
    acc += (c < 32) ? -m : m;
  }
  xn[(long)n * 96 + 32 + c] += 16.f * acc;   // undo 1/16 msg scale
}

// ---------------- pack xn f32 -> xnh f16 pairs ------------------------------
__global__ void pack_xnh(const float* __restrict__ xn, unsigned int* __restrict__ xnh){
  int i = blockIdx.x * 256 + threadIdx.x;
  if (i < NN * 48) xnh[i] = pack2(xn[2*i], xn[2*i+1]);
}

// ---------------- conv layer: f16 node rows, dst-sorted, LUT filters --------
// msg row = 192 f16 halves (384B): p=[0,96) by dst, q=[96,192) by src
// stored value = true/64 (undone in gather_layer)
// pk layout per layer (uints): dw1T[32][96] @0, dw2[192][16] @3072 (6144 total)
// lut row per entry (uints):   WaPairs[48] | WbPairs[48] | WcPairs[96] (192)
__global__ __launch_bounds__(256, 4) void layer_k(
    const int* __restrict__ srcS, const int* __restrict__ dstS,
    const float* __restrict__ els, const unsigned int* __restrict__ xnh,
    unsigned short* __restrict__ msgh, int e0, int e1,
    const unsigned int* __restrict__ lut, const unsigned int* __restrict__ pk)
{
  __shared__ uint4 lw4[1536];          // 24 KB: dw1T + dw2
  unsigned int* lw = (unsigned int*)lw4;
  int t = threadIdx.x;
  {
    const uint4* s4 = (const uint4*)pk;
    for (int i = t; i < 1536; i += 256) lw4[i] = s4[i];
  }
  __syncthreads();
  int p = e0 + blockIdx.x * 256 + t;
  if (p >= e1) return;

  const unsigned int* dw1T = lw;          // [32][96]
  const unsigned int* dw2  = lw + 3072;   // [192][16]

  int s = srcS[p], d = dstS[p];
  float L = els[p];
  float tt = fminf(L * ((float)(NT-1) / 1.7321f), (float)(NT-1) - 0.001f);
  int i0 = (int)tt; float tfv = tt - (float)i0;
  h2f tf2; tf2.x = (_Float16)tfv; tf2.y = tf2.x;
  const unsigned int* rA = lut + (long)i0 * 192;
  const unsigned int* rB = rA + 192;

  const unsigned int* xsh = xnh + s * 48;   // f16 row, 192B
  const unsigned int* xdh = xnh + d * 48;   // sorted: shared across ~16 lanes
  h2f c32; c32.x = (_Float16)0.03125f;  c32.y = c32.x;
  h2f c64; c64.x = (_Float16)0.015625f; c64.y = c64.x;

  float hd[32];
#pragma unroll
  for (int l = 0; l < 32; l++) hd[l] = 0.f;

  // ---- merged A(grad)/B(ave) pass: hd += dw1T^T @ [Wa*(xd-xs); Wb*(xd+xs)/2]
  // g packed at 1/32 scale -> hd holds true/32
  for (int jc = 0; jc < 96; jc += 8){
    int jh = jc >> 1;
    uint4 xsu = *(const uint4*)(xsh + jh);
    uint4 xdu = *(const uint4*)(xdh + jh);
    uint4 aA = *(const uint4*)(rA + jh);
    uint4 bA = *(const uint4*)(rB + jh);
    uint4 aB = *(const uint4*)(rA + 48 + jh);
    uint4 bB = *(const uint4*)(rB + 48 + jh);
    unsigned int xsa[4] = {xsu.x, xsu.y, xsu.z, xsu.w};
    unsigned int xda[4] = {xdu.x, xdu.y, xdu.z, xdu.w};
    unsigned int wA[4] = {lerp2(aA.x,bA.x,tf2), lerp2(aA.y,bA.y,tf2),
                          lerp2(aA.z,bA.z,tf2), lerp2(aA.w,bA.w,tf2)};
    unsigned int wB[4] = {lerp2(aB.x,bB.x,tf2), lerp2(aB.y,bB.y,tf2),
                          lerp2(aB.z,bB.z,tf2), lerp2(aB.w,bB.w,tf2)};
    h2f gpA[4], gpB[4];
#pragma unroll
    for (int q = 0; q < 4; q++){
      h2f hs = u2h(xsa[q]), hdd = u2h(xda[q]);
      h2f dv2 = (hdd - hs) * c32;
      h2f av2 = (hdd + hs) * c64;
      gpA[q] = u2h(wA[q]) * dv2;
      gpB[q] = u2h(wB[q]) * av2;
    }
#pragma unroll
    for (int l = 0; l < 32; l++){
      uint4 w1 = *(const uint4*)(dw1T + l*96 + jh);
      uint4 w2 = *(const uint4*)(dw1T + l*96 + 48 + jh);
      float acc = hd[l];
      acc = dot2(w1.x, gpA[0], acc); acc = dot2(w1.y, gpA[1], acc);
      acc = dot2(w1.z, gpA[2], acc); acc = dot2(w1.w, gpA[3], acc);
      acc = dot2(w2.x, gpB[0], acc); acc = dot2(w2.y, gpB[1], acc);
      acc = dot2(w2.z, gpB[2], acc); acc = dot2(w2.w, gpB[3], acc);
      hd[l] = acc;
    }
  }

  // ---- hd gelu (undo 1/32), pack at 1/64 for output dots ----
  h2f hdp[16];
#pragma unroll
  for (int lp = 0; lp < 16; lp++){
    h2f r;
    r.x = (_Float16)(geluf(32.f*hd[2*lp])   * 0.015625f);
    r.y = (_Float16)(geluf(32.f*hd[2*lp+1]) * 0.015625f);
    hdp[lp] = r;
  }

  // ---- output: dv = Wc[j]*d1, av = 0.5*Wc[96+j]*d2; store p/q at true/64 ---
  unsigned short* mrow = msgh + (long)(p - e0) * 192;
  for (int c0 = 0; c0 < 96; c0 += 32){
    unsigned int pu[16], qu[16];
#pragma unroll
    for (int q4 = 0; q4 < 4; q4++){
      int cb = 96 + (c0 >> 1) + 4*q4;
      uint4 a1 = *(const uint4*)(rA + cb);
      uint4 b1 = *(const uint4*)(rB + cb);
      uint4 a2 = *(const uint4*)(rA + cb + 48);
      uint4 b2 = *(const uint4*)(rB + cb + 48);
      unsigned int c1l[4] = {lerp2(a1.x,b1.x,tf2), lerp2(a1.y,b1.y,tf2),
                             lerp2(a1.z,b1.z,tf2), lerp2(a1.w,b1.w,tf2)};
      unsigned int c2l[4] = {lerp2(a2.x,b2.x,tf2), lerp2(a2.y,b2.y,tf2),
                             lerp2(a2.z,b2.z,tf2), lerp2(a2.w,b2.w,tf2)};
#pragma unroll
      for (int r4 = 0; r4 < 4; r4++){
        int jp = 4*q4 + r4;
        h2f c1h = u2h(c1l[r4]);
        h2f c2h = u2h(c2l[r4]);
        float pv2[2], qv2[2];
#pragma unroll
        for (int w = 0; w < 2; w++){
          int j = c0 + 2*jp + w;
          float d1 = 0.f, d2 = 0.f;
          const uint4* r1 = (const uint4*)(dw2 + j*16);
          const uint4* r2 = (const uint4*)(dw2 + (96+j)*16);
#pragma unroll
          for (int q = 0; q < 4; q++){
            uint4 wa = r1[q], wb = r2[q];
            d1 = dot2(wa.x, hdp[4*q+0], d1); d1 = dot2(wa.y, hdp[4*q+1], d1);
            d1 = dot2(wa.z, hdp[4*q+2], d1); d1 = dot2(wa.w, hdp[4*q+3], d1);
            d2 = dot2(wb.x, hdp[4*q+0], d2); d2 = dot2(wb.y, hdp[4*q+1], d2);
            d2 = dot2(wb.z, hdp[4*q+2], d2); d2 = dot2(wb.w, hdp[4*q+3], d2);
          }
          float c1 = w ? (float)c1h.y : (float)c1h.x;
          float c2 = w ? (float)c2h.y : (float)c2h.x;
          float dv = c1 * d1;           // true/64
          float av = 0.5f * c2 * d2;    // true/64
          pv2[w] = dv + av;
          qv2[w] = av - dv;
        }
        pu[jp] = pack2(pv2[0], pv2[1]);
        qu[jp] = pack2(qv2[0], qv2[1]);
      }
    }
    uint4* pd = (uint4*)(mrow + c0);        // line-aligned full 64B
    uint4* qd = (uint4*)(mrow + 96 + c0);   // line-aligned full 64B
#pragma unroll
    for (int q = 0; q < 4; q++){
      pd[q] = ((uint4*)pu)[q];
      qd[q] = ((uint4*)qu)[q];
    }
  }
}

// 5 nodes per 512-thread block (480 active); dst role streams contiguously
__global__ __launch_bounds__(512) void gather_layer(
    const int* __restrict__ doff, const int* __restrict__ soff,
    const int* __restrict__ sinc, const unsigned short* __restrict__ msgh,
    float* __restrict__ delta, int e0, int e1)
{
  int g = threadIdx.x / 96;
  int c = threadIdx.x - 96 * g;
  if (g >= 5) return;
  int n = blockIdx.x * 5 + g;
  if (n >= NN) return;
  const _Float16* mh = (const _Float16*)msgh;
  float acc = 0.f;
  int lo = doff[n], hi = doff[n+1];
  if (lo < e0) lo = e0;
  if (hi > e1) hi = e1;
  for (int p = lo; p < hi; p++) acc += (float)mh[(long)(p - e0) * 192 + c];
  int s1 = soff[n+1];
  for (int ii = soff[n]; ii < s1; ii++){
    int p = sinc[ii];
    if (p < e0 || p >= e1) continue;
    acc += (float)mh[(long)(p - e0) * 192 + 96 + c];
  }
  delta[(long)n * 96 + c] += 64.f * acc;   // undo 1/64 msg scale
}

// ---------------- xn -= h*delta; re-zero delta; refresh xnh -----------------
__global__ void node_upd(float* __restrict__ xn, float* __restrict__ delta,
                         unsigned int* __restrict__ xnh){
  int i = blockIdx.x * 256 + threadIdx.x;
  if (i >= NN * 48) return;
  float x0 = xn[2*i]   - 0.1f * delta[2*i];
  float x1 = xn[2*i+1] - 0.1f * delta[2*i+1];
  xn[2*i] = x0; xn[2*i+1] = x1;
  delta[2*i] = 0.f; delta[2*i+1] = 0.f;
  xnh[i] = pack2(x0, x1);
}

// ---------------- column sum over nodes -------------------------------------
__global__ void colsum(const float* __restrict__ xn, float* __restrict__ nodesum){
  int col = threadIdx.x % 96;
  int seg = threadIdx.x / 96;
  int stripe = blockIdx.x * 2 + seg;   // 0..399
  float acc = 0.f;
  for (int n = stripe; n < NN; n += 400) acc += xn[(long)n * 96 + col];
  unsafeAtomicAdd(nodesum + col, acc);
}

// ---------------- project to 16 outputs, scale, fp32 store ------------------
__global__ void project(const float* __restrict__ nodesum, const float* __restrict__ siT,
                        float* __restrict__ out){
  int j = threadIdx.x;
  if (j < 16){
    float a = 0.f;
#pragma unroll
    for (int c = 0; c < 96; c++) a += nodesum[c] * siT[j*96 + c];
    out[j] = a * 0.007071067811865475f;   // 1/sqrt(20000)
  }
}

// ---------------- host side -------------------------------------------------
extern "C" void kernel_launch(void* const* d_in, const int* in_sizes, int n_in,
                              void* d_out, int out_size, void* d_ws, size_t ws_size,
                              hipStream_t stream){
  const float* pos  = (const float*)d_in[0];
  const int* atom_z = (const int*)d_in[1];
  const int* esrc   = (const int*)d_in[2];
  const int* edst   = (const int*)d_in[3];

  float* ws      = (float*)d_ws;
  float* xn      = ws;                  // 1,920,000
  float* delta   = ws + 1920000;        // 1,920,000
  float* nodesum = ws + 3840000;        // 96
  float* WB      = ws + 3840096;        // 4,128 fp32 weights
  unsigned int* pk    = (unsigned int*)(ws + 3844224);  // 12,288
  unsigned int* lutL  = (unsigned int*)(ws + 3856512);  // 786,432 (3 MB)
  unsigned int* lut01 = (unsigned int*)(ws + 4642944);  // 65,536
  unsigned int* xnh   = (unsigned int*)(ws + 4708480);  // 960,000 (f16 rows)
  float* els    = ws + 5668480;                 // 320,000 edge lengths
  int*   cntd   = (int*)(ws + 5988480);         // 20,000
  int*   curd   = cntd + 20000;                 // 20,000
  int*   doff   = curd + 20000;                 // 20,004
  int*   cnts   = doff + 20004;                 // 20,000
  int*   curs   = cnts + 20000;                 // 20,000
  int*   soff   = curs + 20000;                 // 20,004
  int*   srcS   = soff + 20004;                 // 320,000
  int*   dstS   = srcS + 320000;                // 320,000
  int*   sinc   = dstS + 320000;                // 320,000 -> end 7,068,488
  unsigned short* msgh = (unsigned short*)(ws + 7068496);  // 64B-aligned f16 msgs

  long wsFloats  = (long)(ws_size / 4);
  long msgHalves = (wsFloats - 7068496L) * 2;
  if (msgHalves < 192 * 1024) msgHalves = 192 * 1024;  // last-resort floor
  long CE  = msgHalves / 192; if (CE > NE) CE = NE;    // layer chunk (192 h/edge)
  long CEi = msgHalves / 64;  if (CEi > NE) CEi = NE;  // init chunk  (64 h/edge)

  float* embedF = WB + 0;        // 160
  float* dl0w1T = WB + 160;      // 256   [32][8]
  float* dl0w2T = WB + 416;      // 1024  [32][32]
  float* dl1w1T = WB + 1440;     // 128   [32][4]
  float* dl1w2T = WB + 1568;     // 1024  [32][32]
  float* siT    = WB + 2592;     // 1536  [16][96]

  hipMemsetAsync(cntd, 0, 20000 * 4, stream);
  hipMemsetAsync(cnts, 0, 20000 * 4, stream);
  hipMemsetAsync(delta, 0, (size_t)NN * 96 * 4, stream);
  hipMemsetAsync(nodesum, 0, 96 * 4, stream);

  TTab tb;
  int ti = 0;
  auto add = [&](const void* s, float* dst, int R, int C, int tr){
    tb.e[ti].src = (const float*)s; tb.e[ti].dst = dst;
    tb.e[ti].R = R; tb.e[ti].C = C; tb.e[ti].trans = tr; ti++;
  };
  add(d_in[4],  embedF, 20, 8, 0);
  add(d_in[5],  dl0w1T, 8, 32, 1);
  add(d_in[6],  dl0w2T, 32, 32, 1);
  add(d_in[7],  dl1w1T, 4, 32, 1);
  add(d_in[8],  dl1w2T, 32, 32, 1);
  add(d_in[17], siT, 96, 16, 1);

  PTab pt;
  int pi = 0;
  auto padd = [&](const void* s, unsigned int* dst, int R, int C){
    pt.e[pi].src = (const float*)s; pt.e[pi].dst = dst;
    pt.e[pi].R = R; pt.e[pi].C = C; pi++;
  };
  for (int i = 0; i < 2; i++){
    padd((const float*)d_in[15] + i*6144, pk + i*6144 + 0,    192, 32);  // dw1T [32][96]
    padd((const float*)d_in[16] + i*6144, pk + i*6144 + 3072, 32, 192);  // dw2  [192][16]
  }

  convw<<<6, 256, 0, stream>>>(tb);
  packw<<<4, 256, 0, stream>>>(pt);
  build_lut<<<2*NT, 384, 0, stream>>>((const float*)d_in[11], (const float*)d_in[12],
                                      (const float*)d_in[13], (const float*)d_in[14],
                                      (unsigned short*)lutL);
  build_lut01<<<NT, 64, 0, stream>>>((const float*)d_in[9], (const float*)d_in[10],
                                     (unsigned short*)lut01);
  count_k<<<(NE + 255)/256, 256, 0, stream>>>(esrc, edst, cntd, cnts);
  prefix_k<<<1, 1024, 0, stream>>>(cntd, doff, curd, NE);
  prefix_k<<<1, 1024, 0, stream>>>(cnts, soff, curs, NE);
  fill_comb<<<(NE + 255)/256, 256, 0, stream>>>(esrc, edst, curd, curs, srcS, dstS, sinc);
  node_init<<<(NN + 255)/256, 256, 0, stream>>>(atom_z, embedF, dl0w1T, dl0w2T, xn);

  for (long e0 = 0; e0 < NE; e0 += CEi){
    long e1 = e0 + CEi; if (e1 > NE) e1 = NE;
    edge_init<<<(int)((e1 - e0 + 255)/256), 256, 0, stream>>>(
        pos, srcS, dstS, els, msgh, (int)e0, (int)e1, dl1w1T, dl1w2T, lut01);
    gather_init<<<(NN + 3)/4, 256, 0, stream>>>(doff, soff, sinc, msgh, xn,
                                                (int)e0, (int)e1);
  }
  pack_xnh<<<(NN*48 + 255)/256, 256, 0, stream>>>(xn, xnh);

  for (int i = 0; i < 2; i++){
    for (long e0 = 0; e0 < NE; e0 += CE){
      long e1 = e0 + CE; if (e1 > NE) e1 = NE;
      layer_k<<<(int)((e1 - e0 + 255)/256), 256, 0, stream>>>(
          srcS, dstS, els, xnh, msgh, (int)e0, (int)e1,
          lutL + (long)i * NT * 192, pk + i*6144);
      gather_layer<<<(NN + 4)/5, 512, 0, stream>>>(doff, soff, sinc, msgh, delta,
                                                   (int)e0, (int)e1);
    }
    node_upd<<<(NN*48 + 255)/256, 256, 0, stream>>>(xn, delta, xnh);
  }
  colsum<<<200, 192, 0, stream>>>(xn, nodesum);
  project<<<1, 64, 0, stream>>>(nodesum, siT, (float*)d_out);
}